// Round 1
// baseline (558.906 us; speedup 1.0000x reference)
//
#include <hip/hip_runtime.h>

#define BATCH 8
#define CC 64
#define NN 4096
#define DQK 8
#define SCL 0.51006973f   // log2(e)/sqrt(8)

typedef __attribute__((ext_vector_type(8))) short s16x8;
typedef __attribute__((ext_vector_type(4))) short s16x4;
typedef __attribute__((ext_vector_type(4))) float f32x4;

__device__ __forceinline__ short f2bf(float f) {
  unsigned u = __builtin_bit_cast(unsigned, f);
  u += 0x7fffu + ((u >> 16) & 1u);
  return (short)(u >> 16);
}

// ---------------- kernel 0: effective weights ----------------
// W_eff[j][o][k]: j in {O,G,I}; k<64 -> w_j[o][k] (h part);
// k>=64 -> sum_t w_j[o][64+t] * wz[t][k-64]  (folds Z=wz*[Zh;Zm]+bz into gates)
// b_eff[j*64+o] = b_j[o] + sum_t w_j[o][64+t]*bz[t]
__global__ void prep_weights_kernel(const float* __restrict__ wz, const float* __restrict__ bz,
                                    const float* __restrict__ wo, const float* __restrict__ bo,
                                    const float* __restrict__ wg, const float* __restrict__ bg,
                                    const float* __restrict__ wi, const float* __restrict__ bi,
                                    short* __restrict__ Weff, float* __restrict__ beff) {
  int i = blockIdx.x * 256 + threadIdx.x;
  const float* wjs[3] = {wo, wg, wi};
  const float* bjs[3] = {bo, bg, bi};
  if (i < 3 * 64 * 192) {
    int j = i / 12288, rem = i % 12288, o = rem / 192, k = rem % 192;
    const float* wj = wjs[j];
    float v;
    if (k < 64) {
      v = wj[o * 128 + k];
    } else {
      v = 0.f;
      for (int t = 0; t < 64; ++t) v += wj[o * 128 + 64 + t] * wz[t * 128 + (k - 64)];
    }
    Weff[i] = f2bf(v);
  } else if (i < 3 * 64 * 192 + 192) {
    int i2 = i - 36864;
    int j = i2 >> 6, o = i2 & 63;
    const float* wj = wjs[j];
    float v = bjs[j][o];
    for (int t = 0; t < 64; ++t) v += wj[o * 128 + 64 + t] * bz[t];
    beff[i2] = v;
  }
}

// ---------------- kernel 1: projections ----------------
// Q,Kh,Km stored transposed [B][N][8] bf16 (16B rows for MFMA frag loads);
// Vh,Vm stored [B][64][N] bf16 (row-contiguous in k for A-frag tiles).
__global__ __launch_bounds__(256) void proj_kernel(
    const float* __restrict__ H_in, const float* __restrict__ M_prev,
    const float* __restrict__ wq, const float* __restrict__ bq,
    const float* __restrict__ wkh, const float* __restrict__ bkh,
    const float* __restrict__ wvh, const float* __restrict__ bvh,
    const float* __restrict__ wkm, const float* __restrict__ bkm,
    const float* __restrict__ wvm, const float* __restrict__ bvm,
    short* __restrict__ Qt, short* __restrict__ Kht, short* __restrict__ Kmt,
    short* __restrict__ Vh, short* __restrict__ Vm) {
  int b = blockIdx.x >> 4;
  int n = ((blockIdx.x & 15) << 8) + threadIdx.x;
  float x[64];

  // ---- phase h ----
  #pragma unroll
  for (int c = 0; c < 64; ++c) x[c] = H_in[((size_t)((b << 6) + c)) * NN + n];
  {
    s16x8 vq, vk;
    #pragma unroll
    for (int o = 0; o < 8; ++o) {
      float aq = bq[o], ak = bkh[o];
      #pragma unroll
      for (int c = 0; c < 64; ++c) { aq += wq[o * 64 + c] * x[c]; ak += wkh[o * 64 + c] * x[c]; }
      vq[o] = f2bf(aq); vk[o] = f2bf(ak);
    }
    *(s16x8*)(Qt + ((size_t)(b * NN + n)) * 8) = vq;
    *(s16x8*)(Kht + ((size_t)(b * NN + n)) * 8) = vk;
  }
  for (int o = 0; o < 64; ++o) {
    float a = bvh[o];
    #pragma unroll
    for (int c = 0; c < 64; ++c) a += wvh[o * 64 + c] * x[c];
    Vh[((size_t)((b << 6) + o)) * NN + n] = f2bf(a);
  }

  // ---- phase m ----
  #pragma unroll
  for (int c = 0; c < 64; ++c) x[c] = M_prev[((size_t)((b << 6) + c)) * NN + n];
  {
    s16x8 vk;
    #pragma unroll
    for (int o = 0; o < 8; ++o) {
      float ak = bkm[o];
      #pragma unroll
      for (int c = 0; c < 64; ++c) ak += wkm[o * 64 + c] * x[c];
      vk[o] = f2bf(ak);
    }
    *(s16x8*)(Kmt + ((size_t)(b * NN + n)) * 8) = vk;
  }
  for (int o = 0; o < 64; ++o) {
    float a = bvm[o];
    #pragma unroll
    for (int c = 0; c < 64; ++c) a += wvm[o * 64 + c] * x[c];
    Vm[((size_t)((b << 6) + o)) * NN + n] = f2bf(a);
  }
}

// ---------------- kernel 2: dual-stream attention ----------------
// Block = (batch, 64-query tile); 4 waves, wave w owns q rows w*16..w*16+15.
// Single pass: unnormalized exp-accumulation + denominator; divide at end.
// Zt output: [B][N][128] bf16, c 0..63 = Zh, 64..127 = Zm.
__global__ __launch_bounds__(256) void attn_kernel(
    const short* __restrict__ Qt, const short* __restrict__ Kht, const short* __restrict__ Kmt,
    const short* __restrict__ Vh, const short* __restrict__ Vm, short* __restrict__ Zt) {
  int b = blockIdx.x >> 6;
  int q0 = (blockIdx.x & 63) << 6;
  int tid = threadIdx.x;
  int w = tid >> 6, l = tid & 63;
  int lg = l >> 4, ll = l & 15;

  __shared__ __align__(16) short Ktile[2][64][8];     // [stream][k][d]
  __shared__ __align__(16) short Vtile[2][64][72];    // [stream][c][k] (+8 pad)
  __shared__ __align__(16) short Pw[4][2][16][72];    // [wave][stream][q][k] (+8 pad)
  __shared__ float dnl[4][2][16];

  // Q fragment (A operand): row q = ll, k(d) = lg*8+b ; zero for d>=8 (lg>0)
  s16x8 aq = {};
  if (lg == 0) aq = *(const s16x8*)(Qt + ((size_t)(b * NN + q0 + w * 16 + ll)) * 8);

  const f32x4 fzero = {0.f, 0.f, 0.f, 0.f};
  f32x4 accZ[2][4];
  #pragma unroll
  for (int s = 0; s < 2; ++s)
    #pragma unroll
    for (int cs = 0; cs < 4; ++cs) accZ[s][cs] = fzero;
  float dn[2][4] = {};

  for (int kt = 0; kt < 64; ++kt) {
    int k0 = kt << 6;
    __syncthreads();
    // stage K tiles (transposed [k][8])
    if (tid < 64) {
      *(s16x8*)&Ktile[0][tid][0] = *(const s16x8*)(Kht + ((size_t)(b * NN + k0 + tid)) * 8);
    } else if (tid < 128) {
      int t = tid - 64;
      *(s16x8*)&Ktile[1][t][0] = *(const s16x8*)(Kmt + ((size_t)(b * NN + k0 + t)) * 8);
    }
    // stage V tiles: 1024 chunks of 16B
    #pragma unroll
    for (int it = 0; it < 4; ++it) {
      int ci = tid + it * 256;
      int s = ci >> 9, r = (ci >> 3) & 63, seg = ci & 7;
      const short* src = (s ? Vm : Vh) + ((size_t)((b << 6) + r)) * NN + k0 + seg * 8;
      *(s16x8*)&Vtile[s][r][seg * 8] = *(const s16x8*)src;
    }
    __syncthreads();

    // scores + exp + P write + denominator
    #pragma unroll
    for (int s = 0; s < 2; ++s) {
      #pragma unroll
      for (int ks = 0; ks < 4; ++ks) {
        s16x8 bk = {};
        if (lg == 0) bk = *(const s16x8*)&Ktile[s][ks * 16 + ll][0];
        f32x4 sc = __builtin_amdgcn_mfma_f32_16x16x32_bf16(aq, bk, fzero, 0, 0, 0);
        #pragma unroll
        for (int r = 0; r < 4; ++r) {
          float p = exp2f(sc[r] * SCL);
          Pw[w][s][lg * 4 + r][ks * 16 + ll] = f2bf(p);
          float t = p;
          t += __shfl_xor(t, 1); t += __shfl_xor(t, 2);
          t += __shfl_xor(t, 4); t += __shfl_xor(t, 8);
          dn[s][r] += t;
        }
      }
    }
    // PV accumulate (per-wave private Pw, no barrier needed)
    #pragma unroll
    for (int s = 0; s < 2; ++s) {
      #pragma unroll
      for (int half = 0; half < 2; ++half) {
        s16x8 bp = *(const s16x8*)&Pw[w][s][ll][half * 32 + lg * 8];
        #pragma unroll
        for (int cs = 0; cs < 4; ++cs) {
          s16x8 av = *(const s16x8*)&Vtile[s][cs * 16 + ll][half * 32 + lg * 8];
          accZ[s][cs] = __builtin_amdgcn_mfma_f32_16x16x32_bf16(av, bp, accZ[s][cs], 0, 0, 0);
        }
      }
    }
  }

  // denominators -> per-wave LDS broadcast (row-group layout -> col layout)
  if (ll == 0) {
    #pragma unroll
    for (int s = 0; s < 2; ++s)
      #pragma unroll
      for (int r = 0; r < 4; ++r) dnl[w][s][lg * 4 + r] = dn[s][r];
  }
  __syncthreads();
  float rd0 = 1.f / dnl[w][0][ll];
  float rd1 = 1.f / dnl[w][1][ll];

  #pragma unroll
  for (int s = 0; s < 2; ++s) {
    float rd = s ? rd1 : rd0;
    #pragma unroll
    for (int cs = 0; cs < 4; ++cs) {
      s16x4 o4;
      #pragma unroll
      for (int r = 0; r < 4; ++r) o4[r] = f2bf(accZ[s][cs][r] * rd);
      *(s16x4*)(Zt + ((size_t)(b * NN + q0 + w * 16 + ll)) * 128 + s * 64 + cs * 16 + lg * 4) = o4;
    }
  }
}

// ---------------- kernel 3: fused gates + elementwise ----------------
// Y[192][n] = W_eff[192][192] * [h; Zh; Zm] + b_eff, then sigmoid/tanh + cell update.
__global__ __launch_bounds__(256) void gates_kernel(
    const float* __restrict__ H_in, const float* __restrict__ M_prev,
    const short* __restrict__ Zt, const short* __restrict__ Weff,
    const float* __restrict__ beff, float* __restrict__ out) {
  int b = blockIdx.x >> 6;
  int n0 = (blockIdx.x & 63) << 6;
  int tid = threadIdx.x, w = tid >> 6, l = tid & 63, lg = l >> 4, ll = l & 15;
  __shared__ __align__(16) short Xt[64][200];  // [n][k] stack, +8 pad

  // h rows (transposed staging, f32->bf16)
  for (int i = tid; i < 512; i += 256) {
    int k = i >> 3, ns = i & 7;
    const float* src = H_in + ((size_t)((b << 6) + k)) * NN + n0 + ns * 8;
    #pragma unroll
    for (int j2 = 0; j2 < 8; ++j2) Xt[ns * 8 + j2][k] = f2bf(src[j2]);
  }
  // Z rows (already [n][128] bf16)
  for (int i = tid; i < 1024; i += 256) {
    int n = i >> 4, seg = i & 15;
    *(s16x8*)&Xt[n][64 + seg * 8] =
        *(const s16x8*)(Zt + ((size_t)(b * NN + n0 + n)) * 128 + seg * 8);
  }
  __syncthreads();

  f32x4 acc[3][4];
  #pragma unroll
  for (int j = 0; j < 3; ++j)
    #pragma unroll
    for (int cs = 0; cs < 4; ++cs)
      #pragma unroll
      for (int r = 0; r < 4; ++r) acc[j][cs][r] = beff[j * 64 + cs * 16 + lg * 4 + r];

  #pragma unroll
  for (int kk = 0; kk < 6; ++kk) {
    s16x8 bx = *(const s16x8*)&Xt[w * 16 + ll][kk * 32 + lg * 8];
    #pragma unroll
    for (int j = 0; j < 3; ++j) {
      #pragma unroll
      for (int cs = 0; cs < 4; ++cs) {
        s16x8 aw = *(const s16x8*)(Weff + ((size_t)(j * 64 + cs * 16 + ll)) * 192 + kk * 32 + lg * 8);
        acc[j][cs] = __builtin_amdgcn_mfma_f32_16x16x32_bf16(aw, bx, acc[j][cs], 0, 0, 0);
      }
    }
  }

  float* Hout = out;
  float* Mout = out + (size_t)BATCH * CC * NN;
  #pragma unroll
  for (int cs = 0; cs < 4; ++cs) {
    #pragma unroll
    for (int r = 0; r < 4; ++r) {
      int c = cs * 16 + lg * 4 + r;
      int n = n0 + w * 16 + ll;
      size_t idx = ((size_t)((b << 6) + c)) * NN + n;
      float xo = acc[0][cs][r], xg = acc[1][cs][r], xi = acc[2][cs][r];
      float o  = 1.f / (1.f + exp2f(-1.44269504f * xo));
      float g  = 2.f / (1.f + exp2f(-2.88539008f * xg)) - 1.f;
      float ii = 1.f / (1.f + exp2f(-1.44269504f * xi));
      float m  = M_prev[idx];
      float mt = (1.f - ii) * m + ii * g;
      Mout[idx] = mt;
      Hout[idx] = o * mt;
    }
  }
}

extern "C" void kernel_launch(void* const* d_in, const int* in_sizes, int n_in,
                              void* d_out, int out_size, void* d_ws, size_t ws_size,
                              hipStream_t stream) {
  (void)in_sizes; (void)n_in; (void)out_size; (void)ws_size;
  const float* H_in  = (const float*)d_in[0];
  const float* M_prev= (const float*)d_in[1];
  const float* wq  = (const float*)d_in[2];
  const float* bq  = (const float*)d_in[3];
  const float* wkh = (const float*)d_in[4];
  const float* bkh = (const float*)d_in[5];
  const float* wvh = (const float*)d_in[6];
  const float* bvh = (const float*)d_in[7];
  const float* wkm = (const float*)d_in[8];
  const float* bkm = (const float*)d_in[9];
  const float* wvm = (const float*)d_in[10];
  const float* bvm = (const float*)d_in[11];
  const float* wz  = (const float*)d_in[12];
  const float* bz  = (const float*)d_in[13];
  const float* wo  = (const float*)d_in[14];
  const float* bo  = (const float*)d_in[15];
  const float* wg  = (const float*)d_in[16];
  const float* bg  = (const float*)d_in[17];
  const float* wi  = (const float*)d_in[18];
  const float* bi  = (const float*)d_in[19];

  char* ws = (char*)d_ws;
  size_t off = 0;
  auto alloc = [&](size_t bytes) -> void* {
    void* p = ws + off;
    off += (bytes + 255) & ~(size_t)255;
    return p;
  };
  short* Weff = (short*)alloc(3 * 64 * 192 * 2);           // 73728
  float* beff = (float*)alloc(192 * 4);
  short* Qt   = (short*)alloc((size_t)BATCH * NN * 8 * 2); // 512KB
  short* Kht  = (short*)alloc((size_t)BATCH * NN * 8 * 2);
  short* Kmt  = (short*)alloc((size_t)BATCH * NN * 8 * 2);
  short* Vh   = (short*)alloc((size_t)BATCH * CC * NN * 2); // 4MB
  short* Vm   = (short*)alloc((size_t)BATCH * CC * NN * 2);
  short* Zt   = (short*)alloc((size_t)BATCH * NN * 128 * 2); // 8MB
  // total ~18.6 MB of workspace

  prep_weights_kernel<<<145, 256, 0, stream>>>(wz, bz, wo, bo, wg, bg, wi, bi, Weff, beff);
  proj_kernel<<<128, 256, 0, stream>>>(H_in, M_prev, wq, bq, wkh, bkh, wvh, bvh,
                                       wkm, bkm, wvm, bvm, Qt, Kht, Kmt, Vh, Vm);
  attn_kernel<<<512, 256, 0, stream>>>(Qt, Kht, Kmt, Vh, Vm, Zt);
  gates_kernel<<<512, 256, 0, stream>>>(H_in, M_prev, Zt, Weff, beff, (float*)d_out);
}

// Round 2
// 307.574 us; speedup vs baseline: 1.8171x; 1.8171x over previous
//
#include <hip/hip_runtime.h>

#define BATCH 8
#define CC 64
#define NN 4096
#define SCL 0.51006973f   // log2(e)/sqrt(8), folded into Q at projection time

typedef __attribute__((ext_vector_type(8))) short s16x8;
typedef __attribute__((ext_vector_type(4))) short s16x4;
typedef __attribute__((ext_vector_type(4))) float f32x4;
typedef __attribute__((ext_vector_type(2))) unsigned int u32x2;

__device__ __forceinline__ short f2bf(float f) {
  unsigned u = __builtin_bit_cast(unsigned, f);
  u += 0x7fffu + ((u >> 16) & 1u);
  return (short)(u >> 16);
}

__device__ __forceinline__ unsigned cvt_pk_bf16(float lo, float hi) {
  unsigned r;
  asm volatile("v_cvt_pk_bf16_f32 %0, %1, %2" : "=v"(r) : "v"(lo), "v"(hi));
  return r;
}

// ---------------- kernel 0: effective weights ----------------
__global__ void prep_weights_kernel(const float* __restrict__ wz, const float* __restrict__ bz,
                                    const float* __restrict__ wo, const float* __restrict__ bo,
                                    const float* __restrict__ wg, const float* __restrict__ bg,
                                    const float* __restrict__ wi, const float* __restrict__ bi,
                                    short* __restrict__ Weff, float* __restrict__ beff) {
  int i = blockIdx.x * 256 + threadIdx.x;
  const float* wjs[3] = {wo, wg, wi};
  const float* bjs[3] = {bo, bg, bi};
  if (i < 3 * 64 * 192) {
    int j = i / 12288, rem = i % 12288, o = rem / 192, k = rem % 192;
    const float* wj = wjs[j];
    float v;
    if (k < 64) {
      v = wj[o * 128 + k];
    } else {
      v = 0.f;
      for (int t = 0; t < 64; ++t) v += wj[o * 128 + 64 + t] * wz[t * 128 + (k - 64)];
    }
    Weff[i] = f2bf(v);
  } else if (i < 3 * 64 * 192 + 192) {
    int i2 = i - 36864;
    int j = i2 >> 6, o = i2 & 63;
    const float* wj = wjs[j];
    float v = bjs[j][o];
    for (int t = 0; t < 64; ++t) v += wj[o * 128 + 64 + t] * bz[t];
    beff[i2] = v;
  }
}

// ---------------- kernel 1: projections (4-way part split, grid 512) ----------------
// part 0: Q(*SCL)+Kh from h; part 1: Vh; part 2: Km from m; part 3: Vm.
__global__ __launch_bounds__(256) void proj_kernel(
    const float* __restrict__ H_in, const float* __restrict__ M_prev,
    const float* __restrict__ wq, const float* __restrict__ bq,
    const float* __restrict__ wkh, const float* __restrict__ bkh,
    const float* __restrict__ wvh, const float* __restrict__ bvh,
    const float* __restrict__ wkm, const float* __restrict__ bkm,
    const float* __restrict__ wvm, const float* __restrict__ bvm,
    short* __restrict__ Qt, short* __restrict__ Kht, short* __restrict__ Kmt,
    short* __restrict__ Vh, short* __restrict__ Vm) {
  int part = blockIdx.x & 3;
  int nt = (blockIdx.x >> 2) & 15;
  int b = blockIdx.x >> 6;
  int n = (nt << 8) + threadIdx.x;
  float x[64];

  if (part == 0) {
    #pragma unroll
    for (int c = 0; c < 64; ++c) x[c] = H_in[((size_t)((b << 6) + c)) * NN + n];
    s16x8 vq, vk;
    #pragma unroll
    for (int o = 0; o < 8; ++o) {
      float aq = bq[o], ak = bkh[o];
      #pragma unroll
      for (int c = 0; c < 64; ++c) { aq += wq[o * 64 + c] * x[c]; ak += wkh[o * 64 + c] * x[c]; }
      vq[o] = f2bf(aq * SCL); vk[o] = f2bf(ak);
    }
    *(s16x8*)(Qt + ((size_t)(b * NN + n)) * 8) = vq;
    *(s16x8*)(Kht + ((size_t)(b * NN + n)) * 8) = vk;
  } else if (part == 2) {
    #pragma unroll
    for (int c = 0; c < 64; ++c) x[c] = M_prev[((size_t)((b << 6) + c)) * NN + n];
    s16x8 vk;
    #pragma unroll
    for (int o = 0; o < 8; ++o) {
      float ak = bkm[o];
      #pragma unroll
      for (int c = 0; c < 64; ++c) ak += wkm[o * 64 + c] * x[c];
      vk[o] = f2bf(ak);
    }
    *(s16x8*)(Kmt + ((size_t)(b * NN + n)) * 8) = vk;
  } else {
    const float* src = (part == 1) ? H_in : M_prev;
    const float* wv = (part == 1) ? wvh : wvm;
    const float* bv = (part == 1) ? bvh : bvm;
    short* V = (part == 1) ? Vh : Vm;
    #pragma unroll
    for (int c = 0; c < 64; ++c) x[c] = src[((size_t)((b << 6) + c)) * NN + n];
    for (int o = 0; o < 64; ++o) {
      float a = bv[o];
      #pragma unroll
      for (int c = 0; c < 64; ++c) a += wv[o * 64 + c] * x[c];
      V[((size_t)((b << 6) + o)) * NN + n] = f2bf(a);
    }
  }
}

// ---------------- kernel 2: attention (one stream per block) ----------------
// grid 1024 = 8b x 64qt x 2s, XCD-swizzled so XCD x owns batch x.
// Block: 4 waves, wave w owns q rows q0+w*16..+15. Double-buffered V/K staging
// via global_load_lds (pre-swizzled source), per-wave Pt transpose via
// cvt_pk + ds_write_b64 + ds_read_b64_tr_b16. Denominator via ones-MFMA.
__global__ __launch_bounds__(256) void attn_kernel(
    const short* __restrict__ Qt, const short* __restrict__ Kht, const short* __restrict__ Kmt,
    const short* __restrict__ Vh, const short* __restrict__ Vm, short* __restrict__ Zt) {
  unsigned vb = (blockIdx.x & 7) * 128 + (blockIdx.x >> 3);
  int b  = vb >> 7;
  int s  = (vb >> 6) & 1;
  int q0 = (vb & 63) << 6;
  int tid = threadIdx.x;
  int w = tid >> 6, l = tid & 63, lg = l >> 4, ll = l & 15;

  const short* __restrict__ Kp = s ? Kmt : Kht;
  const short* __restrict__ Vp = s ? Vm : Vh;

  __shared__ __align__(16) short Vt[2][64][64];        // linear, XOR-swizzled content
  __shared__ __align__(16) short Ktl[2][64][8];
  __shared__ __align__(16) short Pt[4][16][4][16];     // per-wave [ksub][krow][q]

  // Q fragment: A[m=q=ll][d=lg*8+e], real data only at lg==0 (d=0..7), Q pre-scaled
  s16x8 aq = {};
  if (lg == 0) aq = *(const s16x8*)(Qt + ((size_t)(b * NN + q0 + w * 16 + ll)) * 8);
  s16x8 ones;
  #pragma unroll
  for (int i = 0; i < 8; ++i) ones[i] = (short)0x3F80;  // 1.0bf16

  f32x4 accZ[4];
  f32x4 accDn = {0.f, 0.f, 0.f, 0.f};
  #pragma unroll
  for (int cs = 0; cs < 4; ++cs) accZ[cs] = (f32x4){0.f, 0.f, 0.f, 0.f};

  unsigned ptBase = (unsigned)(unsigned long long)&Pt[w][0][0][0];
  unsigned ptRd = ptBase + (unsigned)(lg * 256);   // + half*1024 + t*128 (group-uniform)

  const int rowA = l >> 3;   // 0..7 within an 8-row staging block
  const int slot = l & 7;    // 16B col-slot

  #define STAGE(buf_, k0_)                                                                   \
    do {                                                                                     \
      _Pragma("unroll")                                                                      \
      for (int j = 0; j < 2; ++j) {                                                          \
        int row = ((w * 2 + j) << 3) + rowA;                                                 \
        const short* src = Vp + ((size_t)((b << 6) + row)) * NN + (k0_) +                    \
                           ((slot ^ (row & 7)) << 3);                                        \
        __builtin_amdgcn_global_load_lds((const __attribute__((address_space(1))) void*)src, \
            (__attribute__((address_space(3))) void*)&Vt[buf_][(w * 2 + j) << 3][0], 16, 0, 0); \
      }                                                                                      \
      if (w == 0) {                                                                          \
        const short* srck = Kp + ((size_t)(b * NN) + (k0_) + l) * 8;                         \
        __builtin_amdgcn_global_load_lds((const __attribute__((address_space(1))) void*)srck,\
            (__attribute__((address_space(3))) void*)&Ktl[buf_][0][0], 16, 0, 0);            \
      }                                                                                      \
    } while (0)

  STAGE(0, 0);
  int buf = 0;
  for (int kt = 0; kt < 64; ++kt) {
    asm volatile("s_waitcnt vmcnt(0)" ::: "memory");
    __builtin_amdgcn_s_barrier();
    if (kt < 63) { STAGE(buf ^ 1, (kt + 1) << 6); }

    // ---- scores: D[q=lg*4+r][key=ks*16+ll] ----
    float p[16];
    #pragma unroll
    for (int ks = 0; ks < 4; ++ks) {
      s16x8 bk = {};
      if (lg == 0) bk = *(const s16x8*)&Ktl[buf][ks * 16 + ll][0];
      f32x4 sc = __builtin_amdgcn_mfma_f32_16x16x32_bf16(aq, bk, (f32x4){0.f,0.f,0.f,0.f}, 0, 0, 0);
      #pragma unroll
      for (int r = 0; r < 4; ++r) p[ks * 4 + r] = exp2f(sc[r]);
    }

    // ---- V fragments (independent of P; overlap their latency under exp/pack) ----
    s16x8 av[2][4];
    #pragma unroll
    for (int half = 0; half < 2; ++half)
      #pragma unroll
      for (int cs = 0; cs < 4; ++cs) {
        int row = cs * 16 + ll;
        int col16 = (half * 4 + lg) ^ (row & 7);
        av[half][cs] = *(const s16x8*)((const short*)&Vt[buf][0][0] + row * 64 + col16 * 8);
      }

    // ---- pack P -> Pt[k][q] (b64 writes) ----
    #pragma unroll
    for (int ks = 0; ks < 4; ++ks) {
      u32x2 pw;
      pw.x = cvt_pk_bf16(p[ks * 4 + 0], p[ks * 4 + 1]);
      pw.y = cvt_pk_bf16(p[ks * 4 + 2], p[ks * 4 + 3]);
      *(u32x2*)&Pt[w][ks * 4 + (ll >> 2)][ll & 3][lg * 4] = pw;
    }
    asm volatile("s_waitcnt lgkmcnt(0)" ::: "memory");
    __builtin_amdgcn_sched_barrier(0);

    // ---- transpose-read P as B-fragments: lane gets Pt[k=32h+8lg+e][q=ll] ----
    u32x2 tr[4];
    #pragma unroll
    for (int hh = 0; hh < 2; ++hh)
      #pragma unroll
      for (int t = 0; t < 2; ++t) {
        unsigned addr = ptRd + (unsigned)(hh * 1024 + t * 128);
        asm volatile("ds_read_b64_tr_b16 %0, %1" : "=v"(tr[hh * 2 + t]) : "v"(addr));
      }
    asm volatile("s_waitcnt lgkmcnt(0)" ::: "memory");
    __builtin_amdgcn_sched_barrier(0);

    // ---- PV + denominator MFMAs ----
    #pragma unroll
    for (int half = 0; half < 2; ++half) {
      union { u32x2 u2[2]; s16x8 v; } cvb;
      cvb.u2[0] = tr[half * 2];
      cvb.u2[1] = tr[half * 2 + 1];
      s16x8 bp = cvb.v;
      accDn = __builtin_amdgcn_mfma_f32_16x16x32_bf16(ones, bp, accDn, 0, 0, 0);
      #pragma unroll
      for (int cs = 0; cs < 4; ++cs)
        accZ[cs] = __builtin_amdgcn_mfma_f32_16x16x32_bf16(av[half][cs], bp, accZ[cs], 0, 0, 0);
    }
    buf ^= 1;
  }

  // ---- normalize + write: lane has q=ll, channels c=cs*16+lg*4+r ----
  float rd = 1.f / accDn[0];
  #pragma unroll
  for (int cs = 0; cs < 4; ++cs) {
    s16x4 o4;
    #pragma unroll
    for (int r = 0; r < 4; ++r) o4[r] = f2bf(accZ[cs][r] * rd);
    *(s16x4*)(Zt + ((size_t)(b * NN + q0 + w * 16 + ll)) * 128 + s * 64 + cs * 16 + lg * 4) = o4;
  }
}

// ---------------- kernel 3: fused gates + elementwise ----------------
__global__ __launch_bounds__(256) void gates_kernel(
    const float* __restrict__ H_in, const float* __restrict__ M_prev,
    const short* __restrict__ Zt, const short* __restrict__ Weff,
    const float* __restrict__ beff, float* __restrict__ out) {
  int b = blockIdx.x >> 6;
  int n0 = (blockIdx.x & 63) << 6;
  int tid = threadIdx.x, w = tid >> 6, l = tid & 63, lg = l >> 4, ll = l & 15;
  __shared__ __align__(16) short Xt[64][200];  // [n][k] stack, +8 pad

  for (int i = tid; i < 512; i += 256) {
    int k = i >> 3, ns = i & 7;
    const float* src = H_in + ((size_t)((b << 6) + k)) * NN + n0 + ns * 8;
    #pragma unroll
    for (int j2 = 0; j2 < 8; ++j2) Xt[ns * 8 + j2][k] = f2bf(src[j2]);
  }
  for (int i = tid; i < 1024; i += 256) {
    int n = i >> 4, seg = i & 15;
    *(s16x8*)&Xt[n][64 + seg * 8] =
        *(const s16x8*)(Zt + ((size_t)(b * NN + n0 + n)) * 128 + seg * 8);
  }
  __syncthreads();

  f32x4 acc[3][4];
  #pragma unroll
  for (int j = 0; j < 3; ++j)
    #pragma unroll
    for (int cs = 0; cs < 4; ++cs)
      #pragma unroll
      for (int r = 0; r < 4; ++r) acc[j][cs][r] = beff[j * 64 + cs * 16 + lg * 4 + r];

  #pragma unroll
  for (int kk = 0; kk < 6; ++kk) {
    s16x8 bx = *(const s16x8*)&Xt[w * 16 + ll][kk * 32 + lg * 8];
    #pragma unroll
    for (int j = 0; j < 3; ++j) {
      #pragma unroll
      for (int cs = 0; cs < 4; ++cs) {
        s16x8 aw = *(const s16x8*)(Weff + ((size_t)(j * 64 + cs * 16 + ll)) * 192 + kk * 32 + lg * 8);
        acc[j][cs] = __builtin_amdgcn_mfma_f32_16x16x32_bf16(aw, bx, acc[j][cs], 0, 0, 0);
      }
    }
  }

  float* Hout = out;
  float* Mout = out + (size_t)BATCH * CC * NN;
  #pragma unroll
  for (int cs = 0; cs < 4; ++cs) {
    #pragma unroll
    for (int r = 0; r < 4; ++r) {
      int c = cs * 16 + lg * 4 + r;
      int n = n0 + w * 16 + ll;
      size_t idx = ((size_t)((b << 6) + c)) * NN + n;
      float xo = acc[0][cs][r], xg = acc[1][cs][r], xi = acc[2][cs][r];
      float o  = 1.f / (1.f + exp2f(-1.44269504f * xo));
      float g  = 2.f / (1.f + exp2f(-2.88539008f * xg)) - 1.f;
      float ii = 1.f / (1.f + exp2f(-1.44269504f * xi));
      float m  = M_prev[idx];
      float mt = (1.f - ii) * m + ii * g;
      Mout[idx] = mt;
      Hout[idx] = o * mt;
    }
  }
}

extern "C" void kernel_launch(void* const* d_in, const int* in_sizes, int n_in,
                              void* d_out, int out_size, void* d_ws, size_t ws_size,
                              hipStream_t stream) {
  (void)in_sizes; (void)n_in; (void)out_size; (void)ws_size;
  const float* H_in  = (const float*)d_in[0];
  const float* M_prev= (const float*)d_in[1];
  const float* wq  = (const float*)d_in[2];
  const float* bq  = (const float*)d_in[3];
  const float* wkh = (const float*)d_in[4];
  const float* bkh = (const float*)d_in[5];
  const float* wvh = (const float*)d_in[6];
  const float* bvh = (const float*)d_in[7];
  const float* wkm = (const float*)d_in[8];
  const float* bkm = (const float*)d_in[9];
  const float* wvm = (const float*)d_in[10];
  const float* bvm = (const float*)d_in[11];
  const float* wz  = (const float*)d_in[12];
  const float* bz  = (const float*)d_in[13];
  const float* wo  = (const float*)d_in[14];
  const float* bo  = (const float*)d_in[15];
  const float* wg  = (const float*)d_in[16];
  const float* bg  = (const float*)d_in[17];
  const float* wi  = (const float*)d_in[18];
  const float* bi  = (const float*)d_in[19];

  char* ws = (char*)d_ws;
  size_t off = 0;
  auto alloc = [&](size_t bytes) -> void* {
    void* p = ws + off;
    off += (bytes + 255) & ~(size_t)255;
    return p;
  };
  short* Weff = (short*)alloc(3 * 64 * 192 * 2);
  float* beff = (float*)alloc(192 * 4);
  short* Qt   = (short*)alloc((size_t)BATCH * NN * 8 * 2);
  short* Kht  = (short*)alloc((size_t)BATCH * NN * 8 * 2);
  short* Kmt  = (short*)alloc((size_t)BATCH * NN * 8 * 2);
  short* Vh   = (short*)alloc((size_t)BATCH * CC * NN * 2);
  short* Vm   = (short*)alloc((size_t)BATCH * CC * NN * 2);
  short* Zt   = (short*)alloc((size_t)BATCH * NN * 128 * 2);

  prep_weights_kernel<<<145, 256, 0, stream>>>(wz, bz, wo, bo, wg, bg, wi, bi, Weff, beff);
  proj_kernel<<<512, 256, 0, stream>>>(H_in, M_prev, wq, bq, wkh, bkh, wvh, bvh,
                                       wkm, bkm, wvm, bvm, Qt, Kht, Kmt, Vh, Vm);
  attn_kernel<<<1024, 256, 0, stream>>>(Qt, Kht, Kmt, Vh, Vm, Zt);
  gates_kernel<<<512, 256, 0, stream>>>(H_in, M_prev, Zt, Weff, beff, (float*)d_out);
}

// Round 3
// 247.995 us; speedup vs baseline: 2.2537x; 1.2402x over previous
//
#include <hip/hip_runtime.h>

#define BATCH 8
#define CC 64
#define NN 4096
#define SCL 0.51006973f   // log2(e)/sqrt(8), folded into Q at projection time

typedef __attribute__((ext_vector_type(8))) short s16x8;
typedef __attribute__((ext_vector_type(4))) short s16x4;
typedef __attribute__((ext_vector_type(4))) float f32x4;
typedef __attribute__((ext_vector_type(2))) unsigned int uint2v;

__device__ __forceinline__ short f2bf(float f) {
  unsigned u = __builtin_bit_cast(unsigned, f);
  u += 0x7fffu + ((u >> 16) & 1u);
  return (short)(u >> 16);
}

__device__ __forceinline__ unsigned cvt_pk_bf16(float lo, float hi) {
  unsigned r;
  asm volatile("v_cvt_pk_bf16_f32 %0, %1, %2" : "=v"(r) : "v"(lo), "v"(hi));
  return r;
}

// ---------------- kernel 0: effective weights (gate-scales folded in) ----------------
// W_eff[j][o][k]: j in {O,G,I}; k<64 -> w_j[o][k]; k>=64 -> (w_j[:,64:] @ wz)[o][k-64]
// Rows scaled by {log2e, 2*log2e, log2e} so gates need only exp2/rcp.
__global__ void prep_weights_kernel(const float* __restrict__ wz, const float* __restrict__ bz,
                                    const float* __restrict__ wo, const float* __restrict__ bo,
                                    const float* __restrict__ wg, const float* __restrict__ bg,
                                    const float* __restrict__ wi, const float* __restrict__ bi,
                                    short* __restrict__ Weff, float* __restrict__ beff) {
  int i = blockIdx.x * 256 + threadIdx.x;
  const float* wjs[3] = {wo, wg, wi};
  const float* bjs[3] = {bo, bg, bi};
  const float gsc[3] = {1.44269504f, 2.88539008f, 1.44269504f};
  if (i < 3 * 64 * 192) {
    int j = i / 12288, rem = i % 12288, o = rem / 192, k = rem % 192;
    const float* wj = wjs[j];
    float v;
    if (k < 64) {
      v = wj[o * 128 + k];
    } else {
      v = 0.f;
      for (int t = 0; t < 64; ++t) v += wj[o * 128 + 64 + t] * wz[t * 128 + (k - 64)];
    }
    Weff[i] = f2bf(v * gsc[j]);
  } else if (i < 3 * 64 * 192 + 192) {
    int i2 = i - 36864;
    int j = i2 >> 6, o = i2 & 63;
    const float* wj = wjs[j];
    float v = bjs[j][o];
    for (int t = 0; t < 64; ++t) v += wj[o * 128 + 64 + t] * bz[t];
    beff[i2] = v * gsc[j];
  }
}

// ---------------- kernel 1: projections (4-way part split, grid 512) ----------------
__global__ __launch_bounds__(256) void proj_kernel(
    const float* __restrict__ H_in, const float* __restrict__ M_prev,
    const float* __restrict__ wq, const float* __restrict__ bq,
    const float* __restrict__ wkh, const float* __restrict__ bkh,
    const float* __restrict__ wvh, const float* __restrict__ bvh,
    const float* __restrict__ wkm, const float* __restrict__ bkm,
    const float* __restrict__ wvm, const float* __restrict__ bvm,
    short* __restrict__ Qt, short* __restrict__ Kht, short* __restrict__ Kmt,
    short* __restrict__ Vh, short* __restrict__ Vm) {
  int part = blockIdx.x & 3;
  int nt = (blockIdx.x >> 2) & 15;
  int b = blockIdx.x >> 6;
  int n = (nt << 8) + threadIdx.x;
  float x[64];

  if (part == 0) {
    #pragma unroll
    for (int c = 0; c < 64; ++c) x[c] = H_in[((size_t)((b << 6) + c)) * NN + n];
    s16x8 vq, vk;
    #pragma unroll
    for (int o = 0; o < 8; ++o) {
      float aq = bq[o], ak = bkh[o];
      #pragma unroll
      for (int c = 0; c < 64; ++c) { aq += wq[o * 64 + c] * x[c]; ak += wkh[o * 64 + c] * x[c]; }
      vq[o] = f2bf(aq * SCL); vk[o] = f2bf(ak);
    }
    *(s16x8*)(Qt + ((size_t)(b * NN + n)) * 8) = vq;
    *(s16x8*)(Kht + ((size_t)(b * NN + n)) * 8) = vk;
  } else if (part == 2) {
    #pragma unroll
    for (int c = 0; c < 64; ++c) x[c] = M_prev[((size_t)((b << 6) + c)) * NN + n];
    s16x8 vk;
    #pragma unroll
    for (int o = 0; o < 8; ++o) {
      float ak = bkm[o];
      #pragma unroll
      for (int c = 0; c < 64; ++c) ak += wkm[o * 64 + c] * x[c];
      vk[o] = f2bf(ak);
    }
    *(s16x8*)(Kmt + ((size_t)(b * NN + n)) * 8) = vk;
  } else {
    const float* src = (part == 1) ? H_in : M_prev;
    const float* wv = (part == 1) ? wvh : wvm;
    const float* bv = (part == 1) ? bvh : bvm;
    short* V = (part == 1) ? Vh : Vm;
    #pragma unroll
    for (int c = 0; c < 64; ++c) x[c] = src[((size_t)((b << 6) + c)) * NN + n];
    for (int o = 0; o < 64; ++o) {
      float a = bv[o];
      #pragma unroll
      for (int c = 0; c < 64; ++c) a += wv[o * 64 + c] * x[c];
      V[((size_t)((b << 6) + o)) * NN + n] = f2bf(a);
    }
  }
}

// ---------------- kernel 2: attention ----------------
// Swapped QK^T (K as A-operand with permuted rows) so the P->PV transpose is
// 8 cvt_pk + 4 self-permlane32_swap, no LDS round-trip. BK=128 staging.
// Per score-MFMA ks=2h+par, A row m holds global key:
//   par=0: h*32 + (m>>2)*8 + (m&3)
//   par=1: h*32 + ((m>>2)^2)*8 + 4 + (m&3)
// Then PV B-frag word w: w<2 from ks=2h (in-lane), w>=2 from ks=2h+1 (lane^32).
__global__ __launch_bounds__(256) void attn_kernel(
    const short* __restrict__ Qt, const short* __restrict__ Kht, const short* __restrict__ Kmt,
    const short* __restrict__ Vh, const short* __restrict__ Vm, short* __restrict__ Zt) {
  unsigned vb = (blockIdx.x & 7) * 128 + (blockIdx.x >> 3);
  int b  = vb >> 7;
  int s  = (vb >> 6) & 1;
  int q0 = (vb & 63) << 6;
  int tid = threadIdx.x;
  int w = tid >> 6, l = tid & 63, lg = l >> 4, ll = l & 15;

  const short* __restrict__ Kp = s ? Kmt : Kht;
  const short* __restrict__ Vp = s ? Vm : Vh;

  __shared__ __align__(16) short Vt[2][64][128];   // 32KB, XOR-swizzled content
  __shared__ __align__(16) short Ktl[2][128][8];   // 4KB

  // Q as B operand: B[k=lg*8+e][n=q=ll]; real data only at lg==0 (d<8), pre-scaled
  s16x8 bq = {};
  if (lg == 0) bq = *(const s16x8*)(Qt + ((size_t)(b * NN + q0 + w * 16 + ll)) * 8);
  s16x8 ones;
  #pragma unroll
  for (int i = 0; i < 8; ++i) ones[i] = (short)0x3F80;

  f32x4 accZ[4];
  f32x4 accDn = {0.f, 0.f, 0.f, 0.f};
  #pragma unroll
  for (int cs = 0; cs < 4; ++cs) accZ[cs] = (f32x4){0.f, 0.f, 0.f, 0.f};

  const int keyE = ((ll >> 2) << 3) + (ll & 3);            // even-ks row perm
  const int keyO = (((ll >> 2) ^ 2) << 3) + 4 + (ll & 3);  // odd-ks row perm
  const bool lo32 = (l < 32);

  #define STAGE(buf_, k0_)                                                                   \
    do {                                                                                     \
      _Pragma("unroll")                                                                      \
      for (int j = 0; j < 4; ++j) {                                                          \
        int brow = j * 16 + w * 4;                                                           \
        int row = brow + (l >> 4);                                                           \
        int slot = l & 15;                                                                   \
        const short* src = Vp + ((size_t)((b << 6) + row)) * NN + (k0_) +                    \
                           ((slot ^ (row & 7)) << 3);                                        \
        __builtin_amdgcn_global_load_lds((const __attribute__((address_space(1))) void*)src, \
            (__attribute__((address_space(3))) void*)&Vt[buf_][brow][0], 16, 0, 0);          \
      }                                                                                      \
      if (w == 0) {                                                                          \
        _Pragma("unroll")                                                                    \
        for (int jk = 0; jk < 2; ++jk) {                                                     \
          const short* srck = Kp + ((size_t)(b * NN) + (k0_) + jk * 64 + l) * 8;             \
          __builtin_amdgcn_global_load_lds((const __attribute__((address_space(1))) void*)srck,\
              (__attribute__((address_space(3))) void*)&Ktl[buf_][jk * 64][0], 16, 0, 0);    \
        }                                                                                    \
      }                                                                                      \
    } while (0)

  STAGE(0, 0);
  int buf = 0;
  for (int kt = 0; kt < 32; ++kt) {
    asm volatile("s_waitcnt vmcnt(0)" ::: "memory");
    __builtin_amdgcn_s_barrier();
    if (kt < 31) { STAGE(buf ^ 1, (kt + 1) << 7); }

    #pragma unroll
    for (int s2 = 0; s2 < 2; ++s2) {
      // ---- scores (K rows permuted; all lanes broadcast-read, Q zero-padded) ----
      float p[4][4];
      #pragma unroll
      for (int hh = 0; hh < 2; ++hh) {
        #pragma unroll
        for (int par = 0; par < 2; ++par) {
          int kp = s2 * 64 + hh * 32 + (par ? keyO : keyE);
          s16x8 ak = *(const s16x8*)&Ktl[buf][kp][0];
          f32x4 sc = __builtin_amdgcn_mfma_f32_16x16x32_bf16(ak, bq, (f32x4){0.f,0.f,0.f,0.f}, 0, 0, 0);
          #pragma unroll
          for (int r = 0; r < 4; ++r) p[hh * 2 + par][r] = __builtin_amdgcn_exp2f(sc[r]);
        }
      }
      // ---- pack ----
      unsigned wkv[4][2];
      #pragma unroll
      for (int ks = 0; ks < 4; ++ks) {
        wkv[ks][0] = cvt_pk_bf16(p[ks][0], p[ks][1]);
        wkv[ks][1] = cvt_pk_bf16(p[ks][2], p[ks][3]);
      }
      // ---- route + PV ----
      #pragma unroll
      for (int hh = 0; hh < 2; ++hh) {
        unsigned o0 = wkv[hh * 2 + 1][0], o1 = wkv[hh * 2 + 1][1];
        uint2v pr0 = __builtin_amdgcn_permlane32_swap(o0, o0, false, false);
        uint2v pr1 = __builtin_amdgcn_permlane32_swap(o1, o1, false, false);
        unsigned sw0 = lo32 ? pr0.y : pr0.x;
        unsigned sw1 = lo32 ? pr1.y : pr1.x;
        union { unsigned u[4]; s16x8 v; } bpu;
        bpu.u[0] = wkv[hh * 2][0];
        bpu.u[1] = wkv[hh * 2][1];
        bpu.u[2] = sw0;
        bpu.u[3] = sw1;
        s16x8 bp = bpu.v;
        accDn = __builtin_amdgcn_mfma_f32_16x16x32_bf16(ones, bp, accDn, 0, 0, 0);
        #pragma unroll
        for (int cs = 0; cs < 4; ++cs) {
          int row = cs * 16 + ll;
          int slot = (s2 << 3) + ((hh * 4 + lg) ^ (row & 7));
          s16x8 av = *(const s16x8*)((const short*)&Vt[buf][0][0] + row * 128 + slot * 8);
          accZ[cs] = __builtin_amdgcn_mfma_f32_16x16x32_bf16(av, bp, accZ[cs], 0, 0, 0);
        }
      }
    }
    buf ^= 1;
  }

  // ---- normalize + write: lane has q=ll, channels c=cs*16+lg*4+r ----
  float rd = __builtin_amdgcn_rcpf(accDn[0]);
  #pragma unroll
  for (int cs = 0; cs < 4; ++cs) {
    s16x4 o4;
    #pragma unroll
    for (int r = 0; r < 4; ++r) o4[r] = f2bf(accZ[cs][r] * rd);
    *(s16x4*)(Zt + ((size_t)(b * NN + q0 + w * 16 + ll)) * 128 + s * 64 + cs * 16 + lg * 4) = o4;
  }
  #undef STAGE
}

// ---------------- kernel 3: fused gates + elementwise ----------------
__global__ __launch_bounds__(256) void gates_kernel(
    const float* __restrict__ H_in, const float* __restrict__ M_prev,
    const short* __restrict__ Zt, const short* __restrict__ Weff,
    const float* __restrict__ beff, float* __restrict__ out) {
  int b = blockIdx.x >> 6;
  int n0 = (blockIdx.x & 63) << 6;
  int tid = threadIdx.x, w = tid >> 6, l = tid & 63, lg = l >> 4, ll = l & 15;
  __shared__ __align__(16) short Xt[64][200];  // [n][k] stack, +8 pad

  for (int i = tid; i < 512; i += 256) {
    int k = i >> 3, ns = i & 7;
    const float* src = H_in + ((size_t)((b << 6) + k)) * NN + n0 + ns * 8;
    #pragma unroll
    for (int j2 = 0; j2 < 8; ++j2) Xt[ns * 8 + j2][k] = f2bf(src[j2]);
  }
  for (int i = tid; i < 1024; i += 256) {
    int n = i >> 4, seg = i & 15;
    *(s16x8*)&Xt[n][64 + seg * 8] =
        *(const s16x8*)(Zt + ((size_t)(b * NN + n0 + n)) * 128 + seg * 8);
  }
  __syncthreads();

  f32x4 acc[3][4];
  #pragma unroll
  for (int j = 0; j < 3; ++j)
    #pragma unroll
    for (int cs = 0; cs < 4; ++cs)
      #pragma unroll
      for (int r = 0; r < 4; ++r) acc[j][cs][r] = beff[j * 64 + cs * 16 + lg * 4 + r];

  #pragma unroll
  for (int kk = 0; kk < 6; ++kk) {
    s16x8 bx = *(const s16x8*)&Xt[w * 16 + ll][kk * 32 + lg * 8];
    #pragma unroll
    for (int j = 0; j < 3; ++j) {
      #pragma unroll
      for (int cs = 0; cs < 4; ++cs) {
        s16x8 aw = *(const s16x8*)(Weff + ((size_t)(j * 64 + cs * 16 + ll)) * 192 + kk * 32 + lg * 8);
        acc[j][cs] = __builtin_amdgcn_mfma_f32_16x16x32_bf16(aw, bx, acc[j][cs], 0, 0, 0);
      }
    }
  }

  float* Hout = out;
  float* Mout = out + (size_t)BATCH * CC * NN;
  #pragma unroll
  for (int cs = 0; cs < 4; ++cs) {
    #pragma unroll
    for (int r = 0; r < 4; ++r) {
      int c = cs * 16 + lg * 4 + r;
      int n = n0 + w * 16 + ll;
      size_t idx = ((size_t)((b << 6) + c)) * NN + n;
      float xo = acc[0][cs][r], xg = acc[1][cs][r], xi = acc[2][cs][r];
      float o  = __builtin_amdgcn_rcpf(1.f + __builtin_amdgcn_exp2f(-xo));
      float g  = 2.f * __builtin_amdgcn_rcpf(1.f + __builtin_amdgcn_exp2f(-xg)) - 1.f;
      float ii = __builtin_amdgcn_rcpf(1.f + __builtin_amdgcn_exp2f(-xi));
      float m  = M_prev[idx];
      float mt = (1.f - ii) * m + ii * g;
      Mout[idx] = mt;
      Hout[idx] = o * mt;
    }
  }
}

extern "C" void kernel_launch(void* const* d_in, const int* in_sizes, int n_in,
                              void* d_out, int out_size, void* d_ws, size_t ws_size,
                              hipStream_t stream) {
  (void)in_sizes; (void)n_in; (void)out_size; (void)ws_size;
  const float* H_in  = (const float*)d_in[0];
  const float* M_prev= (const float*)d_in[1];
  const float* wq  = (const float*)d_in[2];
  const float* bq  = (const float*)d_in[3];
  const float* wkh = (const float*)d_in[4];
  const float* bkh = (const float*)d_in[5];
  const float* wvh = (const float*)d_in[6];
  const float* bvh = (const float*)d_in[7];
  const float* wkm = (const float*)d_in[8];
  const float* bkm = (const float*)d_in[9];
  const float* wvm = (const float*)d_in[10];
  const float* bvm = (const float*)d_in[11];
  const float* wz  = (const float*)d_in[12];
  const float* bz  = (const float*)d_in[13];
  const float* wo  = (const float*)d_in[14];
  const float* bo  = (const float*)d_in[15];
  const float* wg  = (const float*)d_in[16];
  const float* bg  = (const float*)d_in[17];
  const float* wi  = (const float*)d_in[18];
  const float* bi  = (const float*)d_in[19];

  char* ws = (char*)d_ws;
  size_t off = 0;
  auto alloc = [&](size_t bytes) -> void* {
    void* p = ws + off;
    off += (bytes + 255) & ~(size_t)255;
    return p;
  };
  short* Weff = (short*)alloc(3 * 64 * 192 * 2);
  float* beff = (float*)alloc(192 * 4);
  short* Qt   = (short*)alloc((size_t)BATCH * NN * 8 * 2);
  short* Kht  = (short*)alloc((size_t)BATCH * NN * 8 * 2);
  short* Kmt  = (short*)alloc((size_t)BATCH * NN * 8 * 2);
  short* Vh   = (short*)alloc((size_t)BATCH * CC * NN * 2);
  short* Vm   = (short*)alloc((size_t)BATCH * CC * NN * 2);
  short* Zt   = (short*)alloc((size_t)BATCH * NN * 128 * 2);

  prep_weights_kernel<<<145, 256, 0, stream>>>(wz, bz, wo, bo, wg, bg, wi, bi, Weff, beff);
  proj_kernel<<<512, 256, 0, stream>>>(H_in, M_prev, wq, bq, wkh, bkh, wvh, bvh,
                                       wkm, bkm, wvm, bvm, Qt, Kht, Kmt, Vh, Vm);
  attn_kernel<<<1024, 256, 0, stream>>>(Qt, Kht, Kmt, Vh, Vm, Zt);
  gates_kernel<<<512, 256, 0, stream>>>(H_in, M_prev, Zt, Weff, beff, (float*)d_out);
}

// Round 4
// 190.289 us; speedup vs baseline: 2.9371x; 1.3033x over previous
//
#include <hip/hip_runtime.h>

#define BATCH 8
#define CC 64
#define NN 4096
#define SCL 0.51006973f   // log2(e)/sqrt(8), folded into Q weights at prep time

typedef __attribute__((ext_vector_type(8))) short s16x8;
typedef __attribute__((ext_vector_type(4))) short s16x4;
typedef __attribute__((ext_vector_type(4))) float f32x4;
typedef __attribute__((ext_vector_type(2))) unsigned int uint2v;

__device__ __forceinline__ short f2bf(float f) {
  unsigned u = __builtin_bit_cast(unsigned, f);
  u += 0x7fffu + ((u >> 16) & 1u);
  return (short)(u >> 16);
}

__device__ __forceinline__ unsigned cvt_pk_bf16(float lo, float hi) {
  unsigned r;
  asm volatile("v_cvt_pk_bf16_f32 %0, %1, %2" : "=v"(r) : "v"(lo), "v"(hi));
  return r;
}

// key permutation within a 64-group (fragment storage order for attn A-operand)
__device__ __forceinline__ int kperm(int kk) {
  int hh = (kk >> 5) & 1, g = (kk >> 3) & 3, c = kk & 7;
  return hh * 32 + (c < 4 ? (g << 2) + c : 16 + ((g ^ 2) << 2) + (c - 4));
}

// ---------------- kernel 0: effective weights + concatenated proj weights ----------------
__global__ void prep_weights_kernel(const float* __restrict__ wz, const float* __restrict__ bz,
                                    const float* __restrict__ wo, const float* __restrict__ bo,
                                    const float* __restrict__ wg, const float* __restrict__ bg,
                                    const float* __restrict__ wi, const float* __restrict__ bi,
                                    const float* __restrict__ wq, const float* __restrict__ bq,
                                    const float* __restrict__ wkh, const float* __restrict__ bkh,
                                    const float* __restrict__ wvh, const float* __restrict__ bvh,
                                    const float* __restrict__ wkm, const float* __restrict__ bkm,
                                    const float* __restrict__ wvm, const float* __restrict__ bvm,
                                    short* __restrict__ Weff, float* __restrict__ beff,
                                    short* __restrict__ Wcat, float* __restrict__ bias) {
  int i = blockIdx.x * 256 + threadIdx.x;
  const float* wjs[3] = {wo, wg, wi};
  const float* bjs[3] = {bo, bg, bi};
  const float gsc[3] = {1.44269504f, 2.88539008f, 1.44269504f};
  if (i < 36864) {
    int j = i / 12288, rem = i % 12288, o = rem / 192, k = rem % 192;
    const float* wj = wjs[j];
    float v;
    if (k < 64) {
      v = wj[o * 128 + k];
    } else {
      v = 0.f;
      #pragma unroll 8
      for (int t = 0; t < 64; ++t) v += wj[o * 128 + 64 + t] * wz[t * 128 + (k - 64)];
    }
    Weff[i] = f2bf(v * gsc[j]);
  } else if (i < 37056) {
    int i2 = i - 36864;
    int j = i2 >> 6, o = i2 & 63;
    const float* wj = wjs[j];
    float v = bjs[j][o];
    #pragma unroll 8
    for (int t = 0; t < 64; ++t) v += wj[o * 128 + 64 + t] * bz[t];
    beff[i2] = v * gsc[j];
  } else if (i < 47296) {
    int i2 = i - 37056;
    int src = i2 / 5120, rem = i2 % 5120, row = rem >> 6, col = rem & 63;
    float v;
    if (src == 0) {
      if (row < 64) v = wvh[row * 64 + col];
      else if (row < 72) v = wq[(row - 64) * 64 + col] * SCL;
      else v = wkh[(row - 72) * 64 + col];
    } else {
      if (row < 64) v = wvm[row * 64 + col];
      else if (row < 72) v = wkm[(row - 64) * 64 + col];
      else v = 0.f;
    }
    Wcat[i2] = f2bf(v);
  } else if (i < 47456) {
    int i3 = i - 47296;
    int src = i3 / 80, row = i3 % 80;
    float v;
    if (src == 0) v = (row < 64) ? bvh[row] : (row < 72 ? bq[row - 64] * SCL : bkh[row - 72]);
    else          v = (row < 64) ? bvm[row] : (row < 72 ? bkm[row - 64] : 0.f);
    bias[i3] = v;
  }
}

// ---------------- kernel 1: MFMA projections ----------------
// grid 512 = b(8) x ntile(32) x src(2); block = 4 waves, 128 n-positions.
// Out[80][n] = Wcat[src] @ x + bias. Rows 0..63 -> V; 64..71 -> Q (src0) / Km (src1,
// permuted); 72..79 -> Kh (src0, permuted).
__global__ __launch_bounds__(256) void proj_kernel(
    const float* __restrict__ H_in, const float* __restrict__ M_prev,
    const short* __restrict__ Wcat, const float* __restrict__ bias,
    short* __restrict__ Qt, short* __restrict__ Kht, short* __restrict__ Kmt,
    short* __restrict__ Vh, short* __restrict__ Vm) {
  int src = blockIdx.x & 1;
  int n0 = ((blockIdx.x >> 1) & 31) << 7;
  int b = blockIdx.x >> 6;
  int tid = threadIdx.x, w = tid >> 6, l = tid & 63, lg = l >> 4, ll = l & 15;

  const float* __restrict__ X = src ? M_prev : H_in;
  short* __restrict__ Vp = src ? Vm : Vh;

  __shared__ __align__(16) short Xt[128][68];   // [n][c], +4 pad

  // stage x: thread -> (nl = tid&127, chalf = tid>>7), 32 channels each
  {
    int nl = tid & 127, chalf = (tid >> 7) << 5;
    int n = n0 + nl;
    #pragma unroll
    for (int cg = 0; cg < 8; ++cg) {
      int c = chalf + cg * 4;
      float v0 = X[((size_t)((b << 6) + c + 0)) * NN + n];
      float v1 = X[((size_t)((b << 6) + c + 1)) * NN + n];
      float v2 = X[((size_t)((b << 6) + c + 2)) * NN + n];
      float v3 = X[((size_t)((b << 6) + c + 3)) * NN + n];
      uint2v pk;
      pk.x = cvt_pk_bf16(v0, v1);
      pk.y = cvt_pk_bf16(v2, v3);
      *(uint2v*)&Xt[nl][c] = pk;
    }
  }
  __syncthreads();

  f32x4 acc[5][2];
  #pragma unroll
  for (int ot = 0; ot < 5; ++ot)
    #pragma unroll
    for (int ns = 0; ns < 2; ++ns)
      #pragma unroll
      for (int r = 0; r < 4; ++r) acc[ot][ns][r] = bias[src * 80 + ot * 16 + lg * 4 + r];

  #pragma unroll
  for (int kk = 0; kk < 2; ++kk) {
    s16x8 aw[5];
    #pragma unroll
    for (int ot = 0; ot < 5; ++ot)
      aw[ot] = *(const s16x8*)(Wcat + ((size_t)(src * 80 + ot * 16 + ll)) * 64 + kk * 32 + lg * 8);
    #pragma unroll
    for (int ns = 0; ns < 2; ++ns) {
      s16x8 bx = *(const s16x8*)&Xt[w * 32 + ns * 16 + ll][kk * 32 + lg * 8];
      #pragma unroll
      for (int ot = 0; ot < 5; ++ot)
        acc[ot][ns] = __builtin_amdgcn_mfma_f32_16x16x32_bf16(aw[ot], bx, acc[ot][ns], 0, 0, 0);
    }
  }

  // stores
  #pragma unroll
  for (int ns = 0; ns < 2; ++ns) {
    int n = n0 + w * 32 + ns * 16 + ll;
    #pragma unroll
    for (int ot = 0; ot < 4; ++ot) {
      #pragma unroll
      for (int r = 0; r < 4; ++r) {
        int o = ot * 16 + lg * 4 + r;
        Vp[((size_t)((b << 6) + o)) * NN + n] = f2bf(acc[ot][ns][r]);
      }
    }
    // ot == 4: rows 64..79
    int pr = (n & ~63) + kperm(n & 63);
    #pragma unroll
    for (int r = 0; r < 4; ++r) {
      float v = acc[4][ns][r];
      if (src == 0) {
        if (lg < 2) Qt[((size_t)(b * NN + n)) * 8 + (lg * 4 + r)] = f2bf(v);
        else        Kht[((size_t)(b * NN + pr)) * 8 + ((lg - 2) * 4 + r)] = f2bf(v);
      } else {
        if (lg < 2) Kmt[((size_t)(b * NN + pr)) * 8 + (lg * 4 + r)] = f2bf(v);
      }
    }
  }
}

// ---------------- kernel 2: attention ----------------
// Swapped QK^T; K pre-permuted in memory so A-fragment reads are linear in ll.
// P->PV via cvt_pk + permlane32_swap (no LDS). BK=128 double-buffered staging.
__global__ __launch_bounds__(256) void attn_kernel(
    const short* __restrict__ Qt, const short* __restrict__ Kht, const short* __restrict__ Kmt,
    const short* __restrict__ Vh, const short* __restrict__ Vm, short* __restrict__ Zt) {
  unsigned vb = (blockIdx.x & 7) * 128 + (blockIdx.x >> 3);
  int b  = vb >> 7;
  int s  = (vb >> 6) & 1;
  int q0 = (vb & 63) << 6;
  int tid = threadIdx.x;
  int w = tid >> 6, l = tid & 63, lg = l >> 4, ll = l & 15;

  const short* __restrict__ Kp = s ? Kmt : Kht;
  const short* __restrict__ Vp = s ? Vm : Vh;

  __shared__ __align__(16) short Vt[2][64][128];   // 32KB, XOR-swizzled content
  __shared__ __align__(16) short Ktl[2][128][8];   // 4KB, fragment-ordered rows

  s16x8 bq = {};
  if (lg == 0) bq = *(const s16x8*)(Qt + ((size_t)(b * NN + q0 + w * 16 + ll)) * 8);
  s16x8 ones;
  #pragma unroll
  for (int i = 0; i < 8; ++i) ones[i] = (short)0x3F80;

  f32x4 accZ[4];
  f32x4 accDn = {0.f, 0.f, 0.f, 0.f};
  #pragma unroll
  for (int cs = 0; cs < 4; ++cs) accZ[cs] = (f32x4){0.f, 0.f, 0.f, 0.f};

  const bool lo32 = (l < 32);

  #define STAGE(buf_, k0_)                                                                   \
    do {                                                                                     \
      _Pragma("unroll")                                                                      \
      for (int j = 0; j < 4; ++j) {                                                          \
        int brow = j * 16 + w * 4;                                                           \
        int row = brow + (l >> 4);                                                           \
        int slot = l & 15;                                                                   \
        const short* src = Vp + ((size_t)((b << 6) + row)) * NN + (k0_) +                    \
                           ((slot ^ (row & 7)) << 3);                                        \
        __builtin_amdgcn_global_load_lds((const __attribute__((address_space(1))) void*)src, \
            (__attribute__((address_space(3))) void*)&Vt[buf_][brow][0], 16, 0, 0);          \
      }                                                                                      \
      if (w == 0) {                                                                          \
        _Pragma("unroll")                                                                    \
        for (int jk = 0; jk < 2; ++jk) {                                                     \
          const short* srck = Kp + ((size_t)(b * NN) + (k0_) + jk * 64 + l) * 8;             \
          __builtin_amdgcn_global_load_lds((const __attribute__((address_space(1))) void*)srck,\
              (__attribute__((address_space(3))) void*)&Ktl[buf_][jk * 64][0], 16, 0, 0);    \
        }                                                                                    \
      }                                                                                      \
    } while (0)

  STAGE(0, 0);
  int buf = 0;
  for (int kt = 0; kt < 32; ++kt) {
    asm volatile("s_waitcnt vmcnt(0)" ::: "memory");
    __builtin_amdgcn_s_barrier();
    if (kt < 31) { STAGE(buf ^ 1, (kt + 1) << 7); }

    #pragma unroll
    for (int s2 = 0; s2 < 2; ++s2) {
      // ---- scores (K fragment-ordered: row = par*16+ll within 32-group) ----
      float p[4][4];
      #pragma unroll
      for (int hh = 0; hh < 2; ++hh) {
        #pragma unroll
        for (int par = 0; par < 2; ++par) {
          s16x8 ak = *(const s16x8*)&Ktl[buf][s2 * 64 + hh * 32 + par * 16 + ll][0];
          f32x4 sc = __builtin_amdgcn_mfma_f32_16x16x32_bf16(ak, bq, (f32x4){0.f,0.f,0.f,0.f}, 0, 0, 0);
          #pragma unroll
          for (int r = 0; r < 4; ++r) p[hh * 2 + par][r] = __builtin_amdgcn_exp2f(sc[r]);
        }
      }
      // ---- pack ----
      unsigned wkv[4][2];
      #pragma unroll
      for (int ks = 0; ks < 4; ++ks) {
        wkv[ks][0] = cvt_pk_bf16(p[ks][0], p[ks][1]);
        wkv[ks][1] = cvt_pk_bf16(p[ks][2], p[ks][3]);
      }
      // ---- route + PV ----
      #pragma unroll
      for (int hh = 0; hh < 2; ++hh) {
        unsigned o0 = wkv[hh * 2 + 1][0], o1 = wkv[hh * 2 + 1][1];
        uint2v pr0 = __builtin_amdgcn_permlane32_swap(o0, o0, false, false);
        uint2v pr1 = __builtin_amdgcn_permlane32_swap(o1, o1, false, false);
        unsigned sw0 = lo32 ? pr0.y : pr0.x;
        unsigned sw1 = lo32 ? pr1.y : pr1.x;
        union { unsigned u[4]; s16x8 v; } bpu;
        bpu.u[0] = wkv[hh * 2][0];
        bpu.u[1] = wkv[hh * 2][1];
        bpu.u[2] = sw0;
        bpu.u[3] = sw1;
        s16x8 bp = bpu.v;
        accDn = __builtin_amdgcn_mfma_f32_16x16x32_bf16(ones, bp, accDn, 0, 0, 0);
        #pragma unroll
        for (int cs = 0; cs < 4; ++cs) {
          int row = cs * 16 + ll;
          int slot = (s2 << 3) + ((hh * 4 + lg) ^ (row & 7));
          s16x8 av = *(const s16x8*)((const short*)&Vt[buf][0][0] + row * 128 + slot * 8);
          accZ[cs] = __builtin_amdgcn_mfma_f32_16x16x32_bf16(av, bp, accZ[cs], 0, 0, 0);
        }
      }
    }
    buf ^= 1;
  }

  float rd = __builtin_amdgcn_rcpf(accDn[0]);
  #pragma unroll
  for (int cs = 0; cs < 4; ++cs) {
    s16x4 o4;
    #pragma unroll
    for (int r = 0; r < 4; ++r) o4[r] = f2bf(accZ[cs][r] * rd);
    *(s16x4*)(Zt + ((size_t)(b * NN + q0 + w * 16 + ll)) * 128 + s * 64 + cs * 16 + lg * 4) = o4;
  }
  #undef STAGE
}

// ---------------- kernel 3: fused gates + elementwise ----------------
// Wave w owns c-quadrant cs=w: rows {j*64 + w*16 + lg*4+r}, all 64 n of the block.
__global__ __launch_bounds__(256) void gates_kernel(
    const float* __restrict__ H_in, const float* __restrict__ M_prev,
    const short* __restrict__ Zt, const short* __restrict__ Weff,
    const float* __restrict__ beff, float* __restrict__ out) {
  int b = blockIdx.x >> 6;
  int n0 = (blockIdx.x & 63) << 6;
  int tid = threadIdx.x, w = tid >> 6, l = tid & 63, lg = l >> 4, ll = l & 15;
  __shared__ __align__(16) short Xt[64][200];  // [n][k] stack, +8 pad

  for (int i = tid; i < 512; i += 256) {
    int k = i >> 3, ns = i & 7;
    const float* src = H_in + ((size_t)((b << 6) + k)) * NN + n0 + ns * 8;
    #pragma unroll
    for (int j2 = 0; j2 < 8; ++j2) Xt[ns * 8 + j2][k] = f2bf(src[j2]);
  }
  for (int i = tid; i < 1024; i += 256) {
    int n = i >> 4, seg = i & 15;
    *(s16x8*)&Xt[n][64 + seg * 8] =
        *(const s16x8*)(Zt + ((size_t)(b * NN + n0 + n)) * 128 + seg * 8);
  }
  __syncthreads();

  f32x4 acc[3][4];
  #pragma unroll
  for (int j = 0; j < 3; ++j) {
    float bj = beff[j * 64 + w * 16 + lg * 4];
    float bj1 = beff[j * 64 + w * 16 + lg * 4 + 1];
    float bj2 = beff[j * 64 + w * 16 + lg * 4 + 2];
    float bj3 = beff[j * 64 + w * 16 + lg * 4 + 3];
    #pragma unroll
    for (int ns = 0; ns < 4; ++ns) {
      acc[j][ns][0] = bj; acc[j][ns][1] = bj1; acc[j][ns][2] = bj2; acc[j][ns][3] = bj3;
    }
  }

  #pragma unroll
  for (int kk = 0; kk < 6; ++kk) {
    s16x8 aw[3];
    #pragma unroll
    for (int j = 0; j < 3; ++j)
      aw[j] = *(const s16x8*)(Weff + ((size_t)(j * 64 + w * 16 + ll)) * 192 + kk * 32 + lg * 8);
    #pragma unroll
    for (int ns = 0; ns < 4; ++ns) {
      s16x8 bx = *(const s16x8*)&Xt[ns * 16 + ll][kk * 32 + lg * 8];
      #pragma unroll
      for (int j = 0; j < 3; ++j)
        acc[j][ns] = __builtin_amdgcn_mfma_f32_16x16x32_bf16(aw[j], bx, acc[j][ns], 0, 0, 0);
    }
  }

  float* Hout = out;
  float* Mout = out + (size_t)BATCH * CC * NN;
  #pragma unroll
  for (int ns = 0; ns < 4; ++ns) {
    #pragma unroll
    for (int r = 0; r < 4; ++r) {
      int c = w * 16 + lg * 4 + r;
      int n = n0 + ns * 16 + ll;
      size_t idx = ((size_t)((b << 6) + c)) * NN + n;
      float xo = acc[0][ns][r], xg = acc[1][ns][r], xi = acc[2][ns][r];
      float o  = __builtin_amdgcn_rcpf(1.f + __builtin_amdgcn_exp2f(-xo));
      float g  = 2.f * __builtin_amdgcn_rcpf(1.f + __builtin_amdgcn_exp2f(-xg)) - 1.f;
      float ii = __builtin_amdgcn_rcpf(1.f + __builtin_amdgcn_exp2f(-xi));
      float m  = M_prev[idx];
      float mt = (1.f - ii) * m + ii * g;
      Mout[idx] = mt;
      Hout[idx] = o * mt;
    }
  }
}

extern "C" void kernel_launch(void* const* d_in, const int* in_sizes, int n_in,
                              void* d_out, int out_size, void* d_ws, size_t ws_size,
                              hipStream_t stream) {
  (void)in_sizes; (void)n_in; (void)out_size; (void)ws_size;
  const float* H_in  = (const float*)d_in[0];
  const float* M_prev= (const float*)d_in[1];
  const float* wq  = (const float*)d_in[2];
  const float* bq  = (const float*)d_in[3];
  const float* wkh = (const float*)d_in[4];
  const float* bkh = (const float*)d_in[5];
  const float* wvh = (const float*)d_in[6];
  const float* bvh = (const float*)d_in[7];
  const float* wkm = (const float*)d_in[8];
  const float* bkm = (const float*)d_in[9];
  const float* wvm = (const float*)d_in[10];
  const float* bvm = (const float*)d_in[11];
  const float* wz  = (const float*)d_in[12];
  const float* bz  = (const float*)d_in[13];
  const float* wo  = (const float*)d_in[14];
  const float* bo  = (const float*)d_in[15];
  const float* wg  = (const float*)d_in[16];
  const float* bg  = (const float*)d_in[17];
  const float* wi  = (const float*)d_in[18];
  const float* bi  = (const float*)d_in[19];

  char* ws = (char*)d_ws;
  size_t off = 0;
  auto alloc = [&](size_t bytes) -> void* {
    void* p = ws + off;
    off += (bytes + 255) & ~(size_t)255;
    return p;
  };
  short* Weff = (short*)alloc(3 * 64 * 192 * 2);
  float* beff = (float*)alloc(192 * 4);
  short* Wcat = (short*)alloc(2 * 80 * 64 * 2);
  float* bias = (float*)alloc(160 * 4);
  short* Qt   = (short*)alloc((size_t)BATCH * NN * 8 * 2);
  short* Kht  = (short*)alloc((size_t)BATCH * NN * 8 * 2);
  short* Kmt  = (short*)alloc((size_t)BATCH * NN * 8 * 2);
  short* Vh   = (short*)alloc((size_t)BATCH * CC * NN * 2);
  short* Vm   = (short*)alloc((size_t)BATCH * CC * NN * 2);
  short* Zt   = (short*)alloc((size_t)BATCH * NN * 128 * 2);

  prep_weights_kernel<<<186, 256, 0, stream>>>(wz, bz, wo, bo, wg, bg, wi, bi,
                                               wq, bq, wkh, bkh, wvh, bvh, wkm, bkm, wvm, bvm,
                                               Weff, beff, Wcat, bias);
  proj_kernel<<<512, 256, 0, stream>>>(H_in, M_prev, Wcat, bias, Qt, Kht, Kmt, Vh, Vm);
  attn_kernel<<<1024, 256, 0, stream>>>(Qt, Kht, Kmt, Vh, Vm, Zt);
  gates_kernel<<<512, 256, 0, stream>>>(H_in, M_prev, Zt, Weff, beff, (float*)d_out);
}

// Round 5
// 189.740 us; speedup vs baseline: 2.9456x; 1.0029x over previous
//
#include <hip/hip_runtime.h>

#define BATCH 8
#define CC 64
#define NN 4096
#define SCL 0.51006973f   // log2(e)/sqrt(8), folded into Q weights at prep time

typedef __attribute__((ext_vector_type(8))) short s16x8;
typedef __attribute__((ext_vector_type(4))) short s16x4;
typedef __attribute__((ext_vector_type(4))) float f32x4;
typedef __attribute__((ext_vector_type(2))) unsigned int uint2v;

__device__ __forceinline__ short f2bf(float f) {
  unsigned u = __builtin_bit_cast(unsigned, f);
  u += 0x7fffu + ((u >> 16) & 1u);
  return (short)(u >> 16);
}
__device__ __forceinline__ float bf2f(short h) {
  unsigned u = ((unsigned)(unsigned short)h) << 16;
  return __builtin_bit_cast(float, u);
}
__device__ __forceinline__ unsigned cvt_pk_bf16(float lo, float hi) {
  unsigned r;
  asm volatile("v_cvt_pk_bf16_f32 %0, %1, %2" : "=v"(r) : "v"(lo), "v"(hi));
  return r;
}

// key permutation within a 64-group (fragment storage order for attn A-operand)
__device__ __forceinline__ int kperm(int kk) {
  int hh = (kk >> 5) & 1, g = (kk >> 3) & 3, c = kk & 7;
  return hh * 32 + (c < 4 ? (g << 2) + c : 16 + ((g ^ 2) << 2) + (c - 4));
}

// ---------------- kernel 0: effective weights + concatenated proj weights ----------------
__global__ void prep_weights_kernel(const float* __restrict__ wz, const float* __restrict__ bz,
                                    const float* __restrict__ wo, const float* __restrict__ bo,
                                    const float* __restrict__ wg, const float* __restrict__ bg,
                                    const float* __restrict__ wi, const float* __restrict__ bi,
                                    const float* __restrict__ wq, const float* __restrict__ bq,
                                    const float* __restrict__ wkh, const float* __restrict__ bkh,
                                    const float* __restrict__ wvh, const float* __restrict__ bvh,
                                    const float* __restrict__ wkm, const float* __restrict__ bkm,
                                    const float* __restrict__ wvm, const float* __restrict__ bvm,
                                    short* __restrict__ Weff, float* __restrict__ beff,
                                    short* __restrict__ Wcat, float* __restrict__ bias) {
  int i = blockIdx.x * 256 + threadIdx.x;
  const float* wjs[3] = {wo, wg, wi};
  const float* bjs[3] = {bo, bg, bi};
  const float gsc[3] = {1.44269504f, 2.88539008f, 1.44269504f};
  if (i < 36864) {
    int j = i / 12288, rem = i % 12288, o = rem / 192, k = rem % 192;
    const float* wj = wjs[j];
    float v;
    if (k < 64) {
      v = wj[o * 128 + k];
    } else {
      v = 0.f;
      #pragma unroll 8
      for (int t = 0; t < 64; ++t) v += wj[o * 128 + 64 + t] * wz[t * 128 + (k - 64)];
    }
    Weff[i] = f2bf(v * gsc[j]);
  } else if (i < 37056) {
    int i2 = i - 36864;
    int j = i2 >> 6, o = i2 & 63;
    const float* wj = wjs[j];
    float v = bjs[j][o];
    #pragma unroll 8
    for (int t = 0; t < 64; ++t) v += wj[o * 128 + 64 + t] * bz[t];
    beff[i2] = v * gsc[j];
  } else if (i < 47296) {
    int i2 = i - 37056;
    int src = i2 / 5120, rem = i2 % 5120, row = rem >> 6, col = rem & 63;
    float v;
    if (src == 0) {
      if (row < 64) v = wvh[row * 64 + col];
      else if (row < 72) v = wq[(row - 64) * 64 + col] * SCL;
      else v = wkh[(row - 72) * 64 + col];
    } else {
      if (row < 64) v = wvm[row * 64 + col];
      else if (row < 72) v = wkm[(row - 64) * 64 + col];
      else v = 0.f;
    }
    Wcat[i2] = f2bf(v);
  } else if (i < 47456) {
    int i3 = i - 47296;
    int src = i3 / 80, row = i3 % 80;
    float v;
    if (src == 0) v = (row < 64) ? bvh[row] : (row < 72 ? bq[row - 64] * SCL : bkh[row - 72]);
    else          v = (row < 64) ? bvm[row] : (row < 72 ? bkm[row - 64] : 0.f);
    bias[i3] = v;
  }
}

// ---------------- kernel 1: MFMA projections ----------------
// grid 512 = b(8) x ntile(32) x src(2); 4 waves, 128 n per block.
// Also exports Ht = h^T bf16 [B][N][64] for the gates kernel (src==0 blocks).
__global__ __launch_bounds__(256) void proj_kernel(
    const float* __restrict__ H_in, const float* __restrict__ M_prev,
    const short* __restrict__ Wcat, const float* __restrict__ bias,
    short* __restrict__ Qt, short* __restrict__ Kht, short* __restrict__ Kmt,
    short* __restrict__ Vh, short* __restrict__ Vm, short* __restrict__ Ht) {
  int src = blockIdx.x & 1;
  int n0 = ((blockIdx.x >> 1) & 31) << 7;
  int b = blockIdx.x >> 6;
  int tid = threadIdx.x, w = tid >> 6, l = tid & 63, lg = l >> 4, ll = l & 15;

  const float* __restrict__ X = src ? M_prev : H_in;
  short* __restrict__ Vp = src ? Vm : Vh;

  __shared__ __align__(16) short Xt[128][68];   // [n][c], +4 pad

  {
    int nl = tid & 127, chalf = (tid >> 7) << 5;
    int n = n0 + nl;
    #pragma unroll
    for (int cg = 0; cg < 8; ++cg) {
      int c = chalf + cg * 4;
      float v0 = X[((size_t)((b << 6) + c + 0)) * NN + n];
      float v1 = X[((size_t)((b << 6) + c + 1)) * NN + n];
      float v2 = X[((size_t)((b << 6) + c + 2)) * NN + n];
      float v3 = X[((size_t)((b << 6) + c + 3)) * NN + n];
      uint2v pk;
      pk.x = cvt_pk_bf16(v0, v1);
      pk.y = cvt_pk_bf16(v2, v3);
      *(uint2v*)&Xt[nl][c] = pk;
    }
  }
  __syncthreads();

  // export Ht (h transposed, bf16) while MFMAs run
  if (src == 0) {
    #pragma unroll
    for (int j = 0; j < 4; ++j) {
      int ci = tid + j * 256;
      int n = ci >> 3, seg = ci & 7;
      *(s16x8*)(Ht + ((size_t)(b * NN + n0 + n)) * 64 + seg * 8) = *(const s16x8*)&Xt[n][seg * 8];
    }
  }

  f32x4 acc[5][2];
  #pragma unroll
  for (int ot = 0; ot < 5; ++ot)
    #pragma unroll
    for (int ns = 0; ns < 2; ++ns)
      #pragma unroll
      for (int r = 0; r < 4; ++r) acc[ot][ns][r] = bias[src * 80 + ot * 16 + lg * 4 + r];

  #pragma unroll
  for (int kk = 0; kk < 2; ++kk) {
    s16x8 aw[5];
    #pragma unroll
    for (int ot = 0; ot < 5; ++ot)
      aw[ot] = *(const s16x8*)(Wcat + ((size_t)(src * 80 + ot * 16 + ll)) * 64 + kk * 32 + lg * 8);
    #pragma unroll
    for (int ns = 0; ns < 2; ++ns) {
      s16x8 bx = *(const s16x8*)&Xt[w * 32 + ns * 16 + ll][kk * 32 + lg * 8];
      #pragma unroll
      for (int ot = 0; ot < 5; ++ot)
        acc[ot][ns] = __builtin_amdgcn_mfma_f32_16x16x32_bf16(aw[ot], bx, acc[ot][ns], 0, 0, 0);
    }
  }

  #pragma unroll
  for (int ns = 0; ns < 2; ++ns) {
    int n = n0 + w * 32 + ns * 16 + ll;
    #pragma unroll
    for (int ot = 0; ot < 4; ++ot) {
      #pragma unroll
      for (int r = 0; r < 4; ++r) {
        int o = ot * 16 + lg * 4 + r;
        Vp[((size_t)((b << 6) + o)) * NN + n] = f2bf(acc[ot][ns][r]);
      }
    }
    int pr = (n & ~63) + kperm(n & 63);
    #pragma unroll
    for (int r = 0; r < 4; ++r) {
      float v = acc[4][ns][r];
      if (src == 0) {
        if (lg < 2) Qt[((size_t)(b * NN + n)) * 8 + (lg * 4 + r)] = f2bf(v);
        else        Kht[((size_t)(b * NN + pr)) * 8 + ((lg - 2) * 4 + r)] = f2bf(v);
      } else {
        if (lg < 2) Kmt[((size_t)(b * NN + pr)) * 8 + (lg * 4 + r)] = f2bf(v);
      }
    }
  }
}

// ---------------- kernel 2: attention (key-split 2-way) ----------------
// grid 2048 = kh(2) x b(8) x s(2) x qt(64); BK=64, LDS 18KB -> 6-8 blocks/CU.
// Unnormalized partial Z (bf16) + denominator (f32) out; combine in gates.
__global__ __launch_bounds__(256, 6) void attn_kernel(
    const short* __restrict__ Qt, const short* __restrict__ Kht, const short* __restrict__ Kmt,
    const short* __restrict__ Vh, const short* __restrict__ Vm,
    short* __restrict__ Zp, float* __restrict__ dnb) {
  unsigned vb = (blockIdx.x & 7) * 256 + (blockIdx.x >> 3);
  int kh = vb >> 10;
  int b  = (vb >> 7) & 7;
  int s  = (vb >> 6) & 1;
  int q0 = (vb & 63) << 6;
  int tid = threadIdx.x;
  int w = tid >> 6, l = tid & 63, lg = l >> 4, ll = l & 15;
  const bool lo32 = (l < 32);

  const short* __restrict__ Kp = s ? Kmt : Kht;
  const short* __restrict__ Vp = s ? Vm : Vh;

  __shared__ __align__(16) short Vt[2][64][64];   // 16KB, XOR-swizzled content
  __shared__ __align__(16) short Ktl[2][64][8];   // 2KB, fragment-ordered rows
  short* VtF = &Vt[0][0][0];
  short* KtF = &Ktl[0][0][0];

  s16x8 bq = {};
  if (lg == 0) bq = *(const s16x8*)(Qt + ((size_t)(b * NN + q0 + w * 16 + ll)) * 8);
  s16x8 ones;
  #pragma unroll
  for (int i = 0; i < 8; ++i) ones[i] = (short)0x3F80;

  f32x4 accZ[4];
  f32x4 accDn = {0.f, 0.f, 0.f, 0.f};
  #pragma unroll
  for (int cs = 0; cs < 4; ++cs) accZ[cs] = (f32x4){0.f, 0.f, 0.f, 0.f};

  // hoisted LDS read offsets (shorts)
  const int vOff0 = ll * 64 + ((lg ^ (ll & 7)) << 3);
  const int vOff1 = ll * 64 + (((lg ^ 4) ^ (ll & 7)) << 3);
  const int kOff  = ll * 8;

  // hoisted stage sources (per-lane)
  const int row0 = w * 8 + (l >> 3);
  const int swz  = ((l & 7) ^ (l >> 3)) << 3;
  const short* vsrc0 = Vp + ((size_t)((b << 6) + row0)) * NN + kh * 2048 + swz;
  const short* vsrc1 = Vp + ((size_t)((b << 6) + 32 + row0)) * NN + kh * 2048 + swz;
  const short* ksrc  = Kp + ((size_t)(b * NN) + kh * 2048 + l) * 8;

#define GLDS(src_, dst_) \
  __builtin_amdgcn_global_load_lds((const __attribute__((address_space(1))) void*)(src_), \
                                   (__attribute__((address_space(3))) void*)(dst_), 16, 0, 0)
#define STAGE(bufL, ktL) do { \
    GLDS(vsrc0 + (ktL) * 64, VtF + (bufL) * 4096 + w * 512); \
    GLDS(vsrc1 + (ktL) * 64, VtF + (bufL) * 4096 + 2048 + w * 512); \
    if (w == 0) GLDS(ksrc + (ktL) * 512, KtF + (bufL) * 512); \
  } while (0)

  auto compute = [&](int bufL) {
    float p[4][4];
    #pragma unroll
    for (int hh = 0; hh < 2; ++hh) {
      #pragma unroll
      for (int par = 0; par < 2; ++par) {
        s16x8 ak = *(const s16x8*)(KtF + bufL * 512 + (hh * 32 + par * 16) * 8 + kOff);
        f32x4 sc = __builtin_amdgcn_mfma_f32_16x16x32_bf16(ak, bq, (f32x4){0.f,0.f,0.f,0.f}, 0, 0, 0);
        #pragma unroll
        for (int r = 0; r < 4; ++r) p[hh * 2 + par][r] = __builtin_amdgcn_exp2f(sc[r]);
      }
    }
    unsigned wkv[4][2];
    #pragma unroll
    for (int ks = 0; ks < 4; ++ks) {
      wkv[ks][0] = cvt_pk_bf16(p[ks][0], p[ks][1]);
      wkv[ks][1] = cvt_pk_bf16(p[ks][2], p[ks][3]);
    }
    #pragma unroll
    for (int hh = 0; hh < 2; ++hh) {
      unsigned o0 = wkv[hh * 2 + 1][0], o1 = wkv[hh * 2 + 1][1];
      uint2v pr0 = __builtin_amdgcn_permlane32_swap(o0, o0, false, false);
      uint2v pr1 = __builtin_amdgcn_permlane32_swap(o1, o1, false, false);
      unsigned sw0 = lo32 ? pr0.y : pr0.x;
      unsigned sw1 = lo32 ? pr1.y : pr1.x;
      union { unsigned u[4]; s16x8 v; } bpu;
      bpu.u[0] = wkv[hh * 2][0];
      bpu.u[1] = wkv[hh * 2][1];
      bpu.u[2] = sw0;
      bpu.u[3] = sw1;
      s16x8 bp = bpu.v;
      accDn = __builtin_amdgcn_mfma_f32_16x16x32_bf16(ones, bp, accDn, 0, 0, 0);
      const int vo = hh ? vOff1 : vOff0;
      #pragma unroll
      for (int cs = 0; cs < 4; ++cs) {
        s16x8 av = *(const s16x8*)(VtF + bufL * 4096 + cs * 1024 + vo);
        accZ[cs] = __builtin_amdgcn_mfma_f32_16x16x32_bf16(av, bp, accZ[cs], 0, 0, 0);
      }
    }
  };

  STAGE(0, 0);
  #pragma unroll 1
  for (int kt2 = 0; kt2 < 16; ++kt2) {
    int kt = kt2 * 2;
    asm volatile("s_waitcnt vmcnt(0)" ::: "memory");
    __builtin_amdgcn_s_barrier();
    STAGE(1, kt + 1);
    compute(0);
    asm volatile("s_waitcnt vmcnt(0)" ::: "memory");
    __builtin_amdgcn_s_barrier();
    if (kt2 < 15) STAGE(0, kt + 2);
    compute(1);
  }

  // unnormalized partial out + denominator
  #pragma unroll
  for (int cs = 0; cs < 4; ++cs) {
    s16x4 o4;
    #pragma unroll
    for (int r = 0; r < 4; ++r) o4[r] = f2bf(accZ[cs][r]);
    *(s16x4*)(Zp + ((size_t)((kh * 8 + b) * NN + q0 + w * 16 + ll)) * 128 + s * 64 + cs * 16 + lg * 4) = o4;
  }
  if (l < 16)
    dnb[((size_t)(kh * 16 + b * 2 + s)) * NN + q0 + w * 16 + l] = accDn[0];
#undef STAGE
#undef GLDS
}

// ---------------- kernel 3: fused gates + elementwise ----------------
// grid 1024 = b(8) x ntile(128); 32 n per block. Stages Ht + combined Z into Xt,
// 36 MFMAs, sigmoid/tanh epilogue + cell update.
__global__ __launch_bounds__(256) void gates_kernel(
    const float* __restrict__ M_prev, const short* __restrict__ Ht,
    const short* __restrict__ Zp, const float* __restrict__ dnb,
    const short* __restrict__ Weff, const float* __restrict__ beff,
    float* __restrict__ out) {
  int b = blockIdx.x >> 7;
  int n0 = (blockIdx.x & 127) << 5;
  int tid = threadIdx.x, w = tid >> 6, l = tid & 63, lg = l >> 4, ll = l & 15;
  __shared__ __align__(16) short Xt[32][200];  // [n][k], +8 pad

  {
    int n = tid >> 3, seg = tid & 7;
    *(s16x8*)&Xt[n][seg * 8] = *(const s16x8*)(Ht + ((size_t)(b * NN + n0 + n)) * 64 + seg * 8);
  }
  {
    int n = tid >> 3, cq = tid & 7, sidx = cq >> 2;
    const short* z0 = Zp + ((size_t)(b * NN + n0 + n)) * 128 + cq * 16;
    const short* z1 = Zp + ((size_t)((8 + b) * NN + n0 + n)) * 128 + cq * 16;
    float d0 = dnb[((size_t)(b * 2 + sidx)) * NN + n0 + n];
    float d1 = dnb[((size_t)(16 + b * 2 + sidx)) * NN + n0 + n];
    float rd = __builtin_amdgcn_rcpf(d0 + d1);
    s16x8 a0 = *(const s16x8*)z0;
    s16x8 a1 = *(const s16x8*)z1;
    s16x8 b0 = *(const s16x8*)(z0 + 8);
    s16x8 b1 = *(const s16x8*)(z1 + 8);
    s16x8 o0, o1;
    #pragma unroll
    for (int j = 0; j < 8; ++j) {
      o0[j] = f2bf((bf2f(a0[j]) + bf2f(a1[j])) * rd);
      o1[j] = f2bf((bf2f(b0[j]) + bf2f(b1[j])) * rd);
    }
    *(s16x8*)&Xt[n][64 + cq * 16] = o0;
    *(s16x8*)&Xt[n][64 + cq * 16 + 8] = o1;
  }
  __syncthreads();

  f32x4 acc[3][2];
  #pragma unroll
  for (int j = 0; j < 3; ++j)
    #pragma unroll
    for (int ns = 0; ns < 2; ++ns)
      #pragma unroll
      for (int r = 0; r < 4; ++r) acc[j][ns][r] = beff[j * 64 + w * 16 + lg * 4 + r];

  #pragma unroll
  for (int kk = 0; kk < 6; ++kk) {
    s16x8 aw[3];
    #pragma unroll
    for (int j = 0; j < 3; ++j)
      aw[j] = *(const s16x8*)(Weff + ((size_t)(j * 64 + w * 16 + ll)) * 192 + kk * 32 + lg * 8);
    #pragma unroll
    for (int ns = 0; ns < 2; ++ns) {
      s16x8 bx = *(const s16x8*)&Xt[ns * 16 + ll][kk * 32 + lg * 8];
      #pragma unroll
      for (int j = 0; j < 3; ++j)
        acc[j][ns] = __builtin_amdgcn_mfma_f32_16x16x32_bf16(aw[j], bx, acc[j][ns], 0, 0, 0);
    }
  }

  float* Hout = out;
  float* Mout = out + (size_t)BATCH * CC * NN;
  #pragma unroll
  for (int ns = 0; ns < 2; ++ns) {
    #pragma unroll
    for (int r = 0; r < 4; ++r) {
      int c = w * 16 + lg * 4 + r;
      int n = n0 + ns * 16 + ll;
      size_t idx = ((size_t)((b << 6) + c)) * NN + n;
      float xo = acc[0][ns][r], xg = acc[1][ns][r], xi = acc[2][ns][r];
      float o  = __builtin_amdgcn_rcpf(1.f + __builtin_amdgcn_exp2f(-xo));
      float g  = 2.f * __builtin_amdgcn_rcpf(1.f + __builtin_amdgcn_exp2f(-xg)) - 1.f;
      float ii = __builtin_amdgcn_rcpf(1.f + __builtin_amdgcn_exp2f(-xi));
      float m  = M_prev[idx];
      float mt = (1.f - ii) * m + ii * g;
      Mout[idx] = mt;
      Hout[idx] = o * mt;
    }
  }
}

extern "C" void kernel_launch(void* const* d_in, const int* in_sizes, int n_in,
                              void* d_out, int out_size, void* d_ws, size_t ws_size,
                              hipStream_t stream) {
  (void)in_sizes; (void)n_in; (void)out_size; (void)ws_size;
  const float* H_in  = (const float*)d_in[0];
  const float* M_prev= (const float*)d_in[1];
  const float* wq  = (const float*)d_in[2];
  const float* bq  = (const float*)d_in[3];
  const float* wkh = (const float*)d_in[4];
  const float* bkh = (const float*)d_in[5];
  const float* wvh = (const float*)d_in[6];
  const float* bvh = (const float*)d_in[7];
  const float* wkm = (const float*)d_in[8];
  const float* bkm = (const float*)d_in[9];
  const float* wvm = (const float*)d_in[10];
  const float* bvm = (const float*)d_in[11];
  const float* wz  = (const float*)d_in[12];
  const float* bz  = (const float*)d_in[13];
  const float* wo  = (const float*)d_in[14];
  const float* bo  = (const float*)d_in[15];
  const float* wg  = (const float*)d_in[16];
  const float* bg  = (const float*)d_in[17];
  const float* wi  = (const float*)d_in[18];
  const float* bi  = (const float*)d_in[19];

  char* ws = (char*)d_ws;
  size_t off = 0;
  auto alloc = [&](size_t bytes) -> void* {
    void* p = ws + off;
    off += (bytes + 255) & ~(size_t)255;
    return p;
  };
  short* Weff = (short*)alloc(3 * 64 * 192 * 2);
  float* beff = (float*)alloc(192 * 4);
  short* Wcat = (short*)alloc(2 * 80 * 64 * 2);
  float* bias = (float*)alloc(160 * 4);
  short* Qt   = (short*)alloc((size_t)BATCH * NN * 8 * 2);
  short* Kht  = (short*)alloc((size_t)BATCH * NN * 8 * 2);
  short* Kmt  = (short*)alloc((size_t)BATCH * NN * 8 * 2);
  short* Vh   = (short*)alloc((size_t)BATCH * CC * NN * 2);
  short* Vm   = (short*)alloc((size_t)BATCH * CC * NN * 2);
  short* Ht   = (short*)alloc((size_t)BATCH * NN * 64 * 2);       // 4MB
  short* Zp   = (short*)alloc((size_t)2 * BATCH * NN * 128 * 2);  // 16MB (2 key-halves)
  float* dnb  = (float*)alloc((size_t)2 * BATCH * 2 * NN * 4);    // 512KB

  prep_weights_kernel<<<186, 256, 0, stream>>>(wz, bz, wo, bo, wg, bg, wi, bi,
                                               wq, bq, wkh, bkh, wvh, bvh, wkm, bkm, wvm, bvm,
                                               Weff, beff, Wcat, bias);
  proj_kernel<<<512, 256, 0, stream>>>(H_in, M_prev, Wcat, bias, Qt, Kht, Kmt, Vh, Vm, Ht);
  attn_kernel<<<2048, 256, 0, stream>>>(Qt, Kht, Kmt, Vh, Vm, Zp, dnb);
  gates_kernel<<<1024, 256, 0, stream>>>(M_prev, Ht, Zp, dnb, Weff, beff, (float*)d_out);
}